// Round 8
// baseline (328.962 us; speedup 1.0000x reference)
//
#include <hip/hip_runtime.h>
#include <math.h>

#define BATCH 32
#define NN 512
#define DD 256
#define NUMK 4

typedef __attribute__((ext_vector_type(8))) short bf16x8;
typedef __attribute__((ext_vector_type(4))) float f32x4;
typedef __attribute__((ext_vector_type(4))) unsigned short u16x4;

__device__ __forceinline__ float softplusf(float v) { return log1pf(expf(v)); }

__device__ __forceinline__ unsigned enc_key(float v) {
  unsigned u = __float_as_uint(v);
  return (u & 0x80000000u) ? ~u : (u | 0x80000000u);
}
__device__ __forceinline__ float dec_key(unsigned k) {
  return (k & 0x80000000u) ? __uint_as_float(k & 0x7fffffffu) : __uint_as_float(~k);
}
__device__ __forceinline__ unsigned short f2b(float f) {
  unsigned u = __float_as_uint(f);
  unsigned r = (u + 0x7fffu + ((u >> 16) & 1u)) >> 16;
  return (unsigned short)r;
}
__device__ __forceinline__ float b2f(unsigned short h) {
  return __uint_as_float(((unsigned)h) << 16);
}

#define GLDS(gp, lp)                                                   \
  __builtin_amdgcn_global_load_lds(                                    \
      (__attribute__((address_space(1))) void*)(void*)(gp),            \
      (__attribute__((address_space(3))) void*)(lp), 16, 0, 0)

// ---------- prep: xb=bf16(x)[n][d], xTb=bf16(x^T)[d][n], xT=f32(x^T); zero keys ----------
__global__ __launch_bounds__(256) void k_prep(const float* __restrict__ x,
                                              short* __restrict__ xb,
                                              short* __restrict__ xTb,
                                              float* __restrict__ xT,
                                              unsigned* keys) {
  __shared__ float t[64][65];
  int b = blockIdx.z, n0 = blockIdx.y * 64, d0 = blockIdx.x * 64;
  if (blockIdx.x == 0 && blockIdx.y == 0 && blockIdx.z == 0 && threadIdx.x == 0) {
    keys[0] = 0u; keys[1] = 0u;
  }
  const float* X = x + (size_t)b * NN * DD;
  int col = threadIdx.x & 63, rr = threadIdx.x >> 6;
#pragma unroll
  for (int s = 0; s < 16; ++s) {
    int row = s * 4 + rr;
    float v = X[(size_t)(n0 + row) * DD + d0 + col];
    t[row][col] = v;
    xb[(size_t)b * NN * DD + (size_t)(n0 + row) * DD + d0 + col] = (short)f2b(v);
  }
  __syncthreads();
#pragma unroll
  for (int s = 0; s < 16; ++s) {
    int row = s * 4 + rr;  // d within tile
    float v = t[col][row];
    size_t idx = (size_t)b * DD * NN + (size_t)(d0 + row) * NN + n0 + col;
    xTb[idx] = (short)f2b(v);
    xT[idx] = v;
  }
}

// ---------- GEMM: C[m][c] = sum_k A[m][k]*B[c][k]; 64x64 tile, BK=64, swizzled LDS ----------
// OUTK 0: bf16 transposed store out[c*ldo+m], *scale, fused atomicMax   (c1 Gram)
// OUTK 1: bf16 natural store out[m*ldo+c]                               (F = x^T @ E)
// OUTK 2: bf16 transposed store, scale = P[4+kiter]/DD                  (Mt = (F@c1)^T)
template <int K, int OUTK>
__global__ __launch_bounds__(256) void k_gemm(
    const short* __restrict__ A, size_t sA, int lda,
    const short* __restrict__ Bp, size_t sB, int ldb,
    void* __restrict__ outp, size_t sO, int ldo,
    float scale, unsigned* maxslot, const float* __restrict__ P, int kiter) {
  __shared__ short As[64 * 64];
  __shared__ short Bs[64 * 64];
  const int b = blockIdx.x;
  const int m0 = blockIdx.y * 64, n0 = blockIdx.z * 64;
  const int tid = threadIdx.x, wave = tid >> 6, lane = tid & 63;
  const int ln = lane & 15, kg = lane >> 4;
  const int wr = (wave >> 1) * 32, wc = (wave & 1) * 32;
  const short* Ab = A + (size_t)b * sA;
  const short* Bb = Bp + (size_t)b * sB;
  const int srow = lane >> 3;
  const int sslot = lane & 7;

  f32x4 acc[2][2];
#pragma unroll
  for (int i = 0; i < 2; ++i)
#pragma unroll
    for (int j = 0; j < 2; ++j) acc[i][j] = (f32x4){0.f, 0.f, 0.f, 0.f};

  for (int k0 = 0; k0 < K; k0 += 64) {
    __syncthreads();
#pragma unroll
    for (int p = 0; p < 2; ++p) {
      int row = p * 32 + wave * 8 + srow;
      int sg = sslot ^ (row & 7);
      GLDS(Ab + (size_t)(m0 + row) * lda + k0 + sg * 8, &As[(p * 32 + wave * 8) * 64]);
      GLDS(Bb + (size_t)(n0 + row) * ldb + k0 + sg * 8, &Bs[(p * 32 + wave * 8) * 64]);
    }
    __syncthreads();
    bf16x8 af[2][2], bfr[2][2];
#pragma unroll
    for (int i = 0; i < 2; ++i)
#pragma unroll
      for (int kk = 0; kk < 2; ++kk) {
        int rowA = wr + i * 16 + ln;
        af[i][kk] = *(const bf16x8*)&As[rowA * 64 + (((kk * 4 + kg) ^ (rowA & 7)) * 8)];
        int rowB = wc + i * 16 + ln;
        bfr[i][kk] = *(const bf16x8*)&Bs[rowB * 64 + (((kk * 4 + kg) ^ (rowB & 7)) * 8)];
      }
#pragma unroll
    for (int kk = 0; kk < 2; ++kk)
#pragma unroll
      for (int i = 0; i < 2; ++i)
#pragma unroll
        for (int j = 0; j < 2; ++j)
          acc[i][j] = __builtin_amdgcn_mfma_f32_16x16x32_bf16(af[i][kk], bfr[j][kk],
                                                              acc[i][j], 0, 0, 0);
  }

  unsigned short* ot = (unsigned short*)outp + (size_t)b * sO;
  if (OUTK == 0 || OUTK == 2) {
    float sc = (OUTK == 2) ? P[4 + kiter] * (1.0f / DD) : scale;
    float tmax = -1e30f;
#pragma unroll
    for (int i = 0; i < 2; ++i) {
      int r = m0 + wr + i * 16 + kg * 4;
#pragma unroll
      for (int j = 0; j < 2; ++j) {
        int c = n0 + wc + j * 16 + ln;
        u16x4 pk;
#pragma unroll
        for (int q = 0; q < 4; ++q) {
          float v = acc[i][j][q] * sc;
          if (OUTK == 0) tmax = fmaxf(tmax, v);
          pk[q] = f2b(v);
        }
        *(u16x4*)&ot[(size_t)c * ldo + r] = pk;
      }
    }
    if (OUTK == 0) {
#pragma unroll
      for (int o = 32; o > 0; o >>= 1) tmax = fmaxf(tmax, __shfl_xor(tmax, o));
      __syncthreads();
      float* smf = (float*)As;
      if (lane == 0) smf[wave] = tmax;
      __syncthreads();
      if (tid == 0)
        atomicMax(maxslot, enc_key(fmaxf(fmaxf(smf[0], smf[1]), fmaxf(smf[2], smf[3]))));
    }
  } else {
    // natural store: coalesced across 16 ln-lanes
#pragma unroll
    for (int i = 0; i < 2; ++i)
#pragma unroll
      for (int j = 0; j < 2; ++j) {
        int c = n0 + wc + j * 16 + ln;
#pragma unroll
        for (int q = 0; q < 4; ++q) {
          int r = m0 + wr + i * 16 + kg * 4 + q;
          ot[(size_t)r * ldo + c] = f2b(acc[i][j][q]);
        }
      }
  }
}

// ---------- c2 max only (no store): upper-triangle blocks of x x^T / D ----------
__global__ __launch_bounds__(256) void k_c2max(const short* __restrict__ xb,
                                               unsigned* maxslot) {
  if (blockIdx.y > blockIdx.z) return;
  __shared__ short As[64 * 64];
  __shared__ short Bs[64 * 64];
  const int b = blockIdx.x;
  const int m0 = blockIdx.y * 64, n0 = blockIdx.z * 64;
  const int tid = threadIdx.x, wave = tid >> 6, lane = tid & 63;
  const int ln = lane & 15, kg = lane >> 4;
  const int wr = (wave >> 1) * 32, wc = (wave & 1) * 32;
  const short* Ab = xb + (size_t)b * ((size_t)NN * DD);
  const int srow = lane >> 3;
  const int sslot = lane & 7;

  f32x4 acc[2][2];
#pragma unroll
  for (int i = 0; i < 2; ++i)
#pragma unroll
    for (int j = 0; j < 2; ++j) acc[i][j] = (f32x4){0.f, 0.f, 0.f, 0.f};

  for (int k0 = 0; k0 < DD; k0 += 64) {
    __syncthreads();
#pragma unroll
    for (int p = 0; p < 2; ++p) {
      int row = p * 32 + wave * 8 + srow;
      int sg = sslot ^ (row & 7);
      GLDS(Ab + (size_t)(m0 + row) * DD + k0 + sg * 8, &As[(p * 32 + wave * 8) * 64]);
      GLDS(Ab + (size_t)(n0 + row) * DD + k0 + sg * 8, &Bs[(p * 32 + wave * 8) * 64]);
    }
    __syncthreads();
    bf16x8 af[2][2], bfr[2][2];
#pragma unroll
    for (int i = 0; i < 2; ++i)
#pragma unroll
      for (int kk = 0; kk < 2; ++kk) {
        int rowA = wr + i * 16 + ln;
        af[i][kk] = *(const bf16x8*)&As[rowA * 64 + (((kk * 4 + kg) ^ (rowA & 7)) * 8)];
        int rowB = wc + i * 16 + ln;
        bfr[i][kk] = *(const bf16x8*)&Bs[rowB * 64 + (((kk * 4 + kg) ^ (rowB & 7)) * 8)];
      }
#pragma unroll
    for (int kk = 0; kk < 2; ++kk)
#pragma unroll
      for (int i = 0; i < 2; ++i)
#pragma unroll
        for (int j = 0; j < 2; ++j)
          acc[i][j] = __builtin_amdgcn_mfma_f32_16x16x32_bf16(af[i][kk], bfr[j][kk],
                                                              acc[i][j], 0, 0, 0);
  }
  float tmax = -1e30f;
#pragma unroll
  for (int i = 0; i < 2; ++i)
#pragma unroll
    for (int j = 0; j < 2; ++j)
#pragma unroll
      for (int q = 0; q < 4; ++q) tmax = fmaxf(tmax, acc[i][j][q] * (1.0f / DD));
#pragma unroll
  for (int o = 32; o > 0; o >>= 1) tmax = fmaxf(tmax, __shfl_xor(tmax, o));
  __syncthreads();
  float* smf = (float*)As;
  if (lane == 0) smf[wave] = tmax;
  __syncthreads();
  if (tid == 0)
    atomicMax(maxslot, enc_key(fmaxf(fmaxf(smf[0], smf[1]), fmaxf(smf[2], smf[3]))));
}

// ---------- y-GEMM: y = x @ Mt^T with fused affine epilogue; d-major f32x4 store ----------
// MODE 2: yT = (xT + acc + zT + rho*log_sT)/(rho+a0)   (a1e/D folded into Mt)
// MODE 3: yT = (acc - zT + rho*log_tT)/rho
template <int MODE, int ZFIRST>
__global__ __launch_bounds__(256) void k_ygemm(
    const short* __restrict__ xb, const short* __restrict__ Mt,
    const float* __restrict__ xT, const float* __restrict__ zT,
    const float* __restrict__ Lt, float* __restrict__ yT,
    const float* __restrict__ P, int kiter) {
  __shared__ short As[64 * 64];
  __shared__ short Bs[64 * 64];
  const int b = blockIdx.x;
  const int m0 = blockIdx.y * 64;  // n
  const int n0 = blockIdx.z * 64;  // d
  const int tid = threadIdx.x, wave = tid >> 6, lane = tid & 63;
  const int ln = lane & 15, kg = lane >> 4;
  const int wr = (wave >> 1) * 32, wc = (wave & 1) * 32;
  const short* Ab = xb + (size_t)b * ((size_t)NN * DD);
  const short* Bb = Mt + (size_t)b * ((size_t)DD * DD);
  const size_t base = (size_t)b * ((size_t)NN * DD);
  const int srow = lane >> 3;
  const int sslot = lane & 7;

  f32x4 acc[2][2];
#pragma unroll
  for (int i = 0; i < 2; ++i)
#pragma unroll
    for (int j = 0; j < 2; ++j) acc[i][j] = (f32x4){0.f, 0.f, 0.f, 0.f};

  for (int k0 = 0; k0 < DD; k0 += 64) {
    __syncthreads();
#pragma unroll
    for (int p = 0; p < 2; ++p) {
      int row = p * 32 + wave * 8 + srow;
      int sg = sslot ^ (row & 7);
      GLDS(Ab + (size_t)(m0 + row) * DD + k0 + sg * 8, &As[(p * 32 + wave * 8) * 64]);
      GLDS(Bb + (size_t)(n0 + row) * DD + k0 + sg * 8, &Bs[(p * 32 + wave * 8) * 64]);
    }
    __syncthreads();
    bf16x8 af[2][2], bfr[2][2];
#pragma unroll
    for (int i = 0; i < 2; ++i)
#pragma unroll
      for (int kk = 0; kk < 2; ++kk) {
        int rowA = wr + i * 16 + ln;
        af[i][kk] = *(const bf16x8*)&As[rowA * 64 + (((kk * 4 + kg) ^ (rowA & 7)) * 8)];
        int rowB = wc + i * 16 + ln;
        bfr[i][kk] = *(const bf16x8*)&Bs[rowB * 64 + (((kk * 4 + kg) ^ (rowB & 7)) * 8)];
      }
#pragma unroll
    for (int kk = 0; kk < 2; ++kk)
#pragma unroll
      for (int i = 0; i < 2; ++i)
#pragma unroll
        for (int j = 0; j < 2; ++j)
          acc[i][j] = __builtin_amdgcn_mfma_f32_16x16x32_bf16(af[i][kk], bfr[j][kk],
                                                              acc[i][j], 0, 0, 0);
  }

  const float a0 = P[kiter], rho = P[8 + kiter];
  const float inv = (MODE == 2) ? 1.0f / (rho + a0) : 1.0f / rho;
#pragma unroll
  for (int i = 0; i < 2; ++i)
#pragma unroll
    for (int j = 0; j < 2; ++j) {
      int cd = n0 + wc + j * 16 + ln;            // d row
      int rn = m0 + wr + i * 16 + kg * 4;        // 4 consecutive n
      size_t idx = base + (size_t)cd * NN + rn;
      f32x4 lv = *(const f32x4*)&Lt[idx];
      f32x4 zv;
      if (ZFIRST) zv = (f32x4){0.f, 0.f, 0.f, 0.f};
      else zv = *(const f32x4*)&zT[idx];
      f32x4 o;
      if (MODE == 2) {
        f32x4 xv = *(const f32x4*)&xT[idx];
#pragma unroll
        for (int q = 0; q < 4; ++q)
          o[q] = (xv[q] + acc[i][j][q] + zv[q] + rho * lv[q]) * inv;
      } else {
#pragma unroll
        for (int q = 0; q < 4; ++q)
          o[q] = (acc[i][j][q] - zv[q] + rho * lv[q]) * inv;
      }
      *(f32x4*)&yT[idx] = o;
    }
}

// ---------- misc: s1 = rowsum(c1b), S = colsum(xb), scalar params ----------
__global__ __launch_bounds__(256) void k_misc(const short* __restrict__ c1b,
                                              const short* __restrict__ xb,
                                              float* __restrict__ s1,
                                              float* __restrict__ S,
                                              const float* a0p, const float* a1p,
                                              const float* a2p, const float* a3p,
                                              const float* rhop, float* P,
                                              const unsigned* keys) {
  int bid = blockIdx.x;
  int lane = threadIdx.x & 63;
  if (bid < 2048) {  // c1 rowsums (8192 rows, 4/block)
    int row = bid * 4 + (threadIdx.x >> 6);
    u16x4 v = *(const u16x4*)(c1b + (size_t)row * 256 + lane * 4);
    float s = 0.f;
#pragma unroll
    for (int q = 0; q < 4; ++q) s += b2f(v[q]);
#pragma unroll
    for (int o = 32; o > 0; o >>= 1) s += __shfl_xor(s, o);
    if (lane == 0) s1[row] = s;
  } else if (bid < 2080) {  // S[b][d] = sum_n x[b][n][d]
    int b = bid - 2048;
    int d = threadIdx.x;
    const short* X = xb + (size_t)b * NN * DD;
    float s = 0.f;
    for (int n = 0; n < NN; ++n) s += b2f((unsigned short)X[(size_t)n * DD + d]);
    S[(size_t)b * DD + d] = s;
  } else if (threadIdx.x == 0) {
    float M1 = dec_key(keys[0]);
    float M2 = dec_key(keys[1]);
    float lq0 = logf(1.0f / NN + 1e-8f);
    float lp0 = logf(1.0f / DD + 1e-8f);
    float mu = lq0, eta = lp0, z1 = 0.f, z2 = 0.f;
    for (int k = 0; k < NUMK; ++k) {
      float a0 = softplusf(a0p[k]), a1 = softplusf(a1p[k]);
      float a2 = softplusf(a2p[k]), a3 = softplusf(a3p[k]);
      float rho = softplusf(rhop[k]);
      P[0 + k] = a0;
      P[4 + k] = a1 / (M1 * M2);
      P[8 + k] = rho;
      P[12 + k] = mu;
      P[16 + k] = eta;
      float t1 = mu;
      mu = (a2 * lq0 + rho * t1 - z1) / (a2 + rho);
      z1 += rho * (expf(mu) - expf(t1));
      float s1v = eta;
      eta = (a3 * lp0 + rho * s1v - z2) / (a3 + rho);
      z2 += rho * (expf(eta) - expf(s1v));
    }
  }
}

// ---------- T-softmax (axis=d) on yT columns; one column per 8-lane group ----------
// FIRST: y from xT + rank-1 gw, with r2-dot computed inline from the loaded column.
template <int FIRST>
__global__ __launch_bounds__(512) void k_tsm(
    const float* __restrict__ yT, const float* __restrict__ xT,
    const float* __restrict__ S, const float* __restrict__ s1,
    float* __restrict__ log_tT, short* __restrict__ eTT,
    const float* __restrict__ P, int kiter) {
  const int b = blockIdx.x, n0 = blockIdx.y * 64;
  const int nl = threadIdx.x >> 3, ds = threadIdx.x & 7;
  const int n = n0 + nl;
  const size_t base = (size_t)b * ((size_t)NN * DD);
  float y[32];
  float m = -1e30f;
  if (FIRST) {
    float dot = 0.f;
#pragma unroll
    for (int dk = 0; dk < 32; ++dk) {
      int d = dk * 8 + ds;
      float v = xT[base + (size_t)d * NN + n];
      y[dk] = v;
      dot += v * S[(size_t)b * DD + d];
    }
    dot += __shfl_xor(dot, 1);
    dot += __shfl_xor(dot, 2);
    dot += __shfl_xor(dot, 4);
    const float c0 = logf(1.0f / NN + 1e-8f) + logf(1.0f / DD + 1e-8f);
    float g = P[4] * expf(c0) * dot * (1.0f / DD);
    float inv = 1.0f / (P[8] + P[0]);
#pragma unroll
    for (int dk = 0; dk < 32; ++dk) {
      int d = dk * 8 + ds;
      y[dk] = (y[dk] + g * s1[(size_t)b * DD + d]) * inv;
      m = fmaxf(m, y[dk]);
    }
  } else {
#pragma unroll
    for (int dk = 0; dk < 32; ++dk) {
      int d = dk * 8 + ds;
      float v = yT[base + (size_t)d * NN + n];
      y[dk] = v;
      m = fmaxf(m, v);
    }
  }
  m = fmaxf(m, __shfl_xor(m, 1));
  m = fmaxf(m, __shfl_xor(m, 2));
  m = fmaxf(m, __shfl_xor(m, 4));
  float s = 0.f;
#pragma unroll
  for (int dk = 0; dk < 32; ++dk) s += expf(y[dk] - m);
  s += __shfl_xor(s, 1);
  s += __shfl_xor(s, 2);
  s += __shfl_xor(s, 4);
  const float lse = m + logf(s);
  const float mu = P[12 + kiter];
#pragma unroll
  for (int dk = 0; dk < 32; ++dk) {
    int d = dk * 8 + ds;
    size_t idx = base + (size_t)d * NN + n;
    float lt = mu + y[dk] - lse;
    log_tT[idx] = lt;
    eTT[idx] = (short)f2b(expf(lt));
  }
}

// ---------- S-softmax (axis=n) rows of y2T + eS + dual z-update ----------
template <int ZFIRST>
__global__ __launch_bounds__(256) void k_ssm(
    const float* __restrict__ y2T, const short* __restrict__ eTT,
    float* __restrict__ log_sT, short* __restrict__ eST, float* __restrict__ zT,
    const float* __restrict__ P, int kiter) {
  const int b = blockIdx.x, d0 = blockIdx.y * 32;
  const int wave = threadIdx.x >> 6, lane = threadIdx.x & 63;
  const size_t base = (size_t)b * ((size_t)NN * DD);
  const float rho = P[8 + kiter], eta = P[16 + kiter];
#pragma unroll
  for (int rr = 0; rr < 8; ++rr) {
    int row = d0 + wave * 8 + rr;
    size_t roff = base + (size_t)row * NN + lane * 8;
    f32x4 v0 = *(const f32x4*)&y2T[roff];
    f32x4 v1 = *(const f32x4*)&y2T[roff + 4];
    float m = fmaxf(fmaxf(fmaxf(v0[0], v0[1]), fmaxf(v0[2], v0[3])),
                    fmaxf(fmaxf(v1[0], v1[1]), fmaxf(v1[2], v1[3])));
#pragma unroll
    for (int o = 1; o < 64; o <<= 1) m = fmaxf(m, __shfl_xor(m, o));
    float s = 0.f;
#pragma unroll
    for (int q = 0; q < 4; ++q) s += expf(v0[q] - m) + expf(v1[q] - m);
#pragma unroll
    for (int o = 1; o < 64; o <<= 1) s += __shfl_xor(s, o);
    float lse = m + logf(s);
    f32x4 ls0, ls1, es0, es1;
    u16x4 ev0, ev1;
#pragma unroll
    for (int q = 0; q < 4; ++q) {
      ls0[q] = eta + v0[q] - lse;
      es0[q] = expf(ls0[q]);
      ev0[q] = f2b(es0[q]);
      ls1[q] = eta + v1[q] - lse;
      es1[q] = expf(ls1[q]);
      ev1[q] = f2b(es1[q]);
    }
    *(f32x4*)&log_sT[roff] = ls0;
    *(f32x4*)&log_sT[roff + 4] = ls1;
    *(u16x4*)&eST[roff] = ev0;
    *(u16x4*)&eST[roff + 4] = ev1;
    bf16x8 et = *(const bf16x8*)&eTT[roff];
    f32x4 z0, z1;
    if (ZFIRST) {
      z0 = (f32x4){0.f, 0.f, 0.f, 0.f};
      z1 = z0;
    } else {
      z0 = *(const f32x4*)&zT[roff];
      z1 = *(const f32x4*)&zT[roff + 4];
    }
#pragma unroll
    for (int q = 0; q < 4; ++q) {
      z0[q] += rho * (b2f((unsigned short)et[q]) - es0[q]);
      z1[q] += rho * (b2f((unsigned short)et[4 + q]) - es1[q]);
    }
    *(f32x4*)&zT[roff] = z0;
    *(f32x4*)&zT[roff + 4] = z1;
  }
}

// ---------- output: out[b][d'] = D * sum_n xT * exp(log_tT) ----------
__global__ __launch_bounds__(256) void k_out(const float* __restrict__ xT,
                                             const float* __restrict__ log_tT,
                                             float* __restrict__ out) {
  const int b = blockIdx.x, d0 = blockIdx.y * 32;
  const int wave = threadIdx.x >> 6, lane = threadIdx.x & 63;
  const size_t base = (size_t)b * ((size_t)NN * DD);
#pragma unroll
  for (int rr = 0; rr < 8; ++rr) {
    int row = d0 + wave * 8 + rr;
    size_t roff = base + (size_t)row * NN + lane * 8;
    f32x4 x0 = *(const f32x4*)&xT[roff];
    f32x4 x1 = *(const f32x4*)&xT[roff + 4];
    f32x4 l0 = *(const f32x4*)&log_tT[roff];
    f32x4 l1 = *(const f32x4*)&log_tT[roff + 4];
    float acc = 0.f;
#pragma unroll
    for (int q = 0; q < 4; ++q) acc += x0[q] * expf(l0[q]) + x1[q] * expf(l1[q]);
#pragma unroll
    for (int o = 1; o < 64; o <<= 1) acc += __shfl_xor(acc, o);
    if (lane == 0) out[(size_t)b * DD + row] = (float)DD * acc;
  }
}

// ---------- launch ----------
extern "C" void kernel_launch(void* const* d_in, const int* in_sizes, int n_in,
                              void* d_out, int out_size, void* d_ws, size_t ws_size,
                              hipStream_t stream) {
  const float* x = (const float*)d_in[0];
  const float* a0p = (const float*)d_in[1];
  const float* a1p = (const float*)d_in[2];
  const float* a2p = (const float*)d_in[3];
  const float* a3p = (const float*)d_in[4];
  const float* rhop = (const float*)d_in[5];
  float* out = (float*)d_out;

  const size_t NE = (size_t)BATCH * NN * DD;
  const size_t NE_b = (size_t)NN * DD;
  const size_t C1_b = (size_t)DD * DD;

  float* fws = (float*)d_ws;
  float* xT = fws;                 // NE (f32 x^T, d-major)
  float* yT = fws + NE;            // NE (y / y2 scratch, d-major)
  float* log_tT = fws + 2 * NE;    // NE
  float* log_sT = fws + 3 * NE;    // NE
  float* zT = fws + 4 * NE;        // NE
  float* S = fws + 5 * NE;         // B*D (colsum of x)
  float* s1 = S + BATCH * DD;      // B*D (rowsum of c1b)
  float* P = s1 + BATCH * DD;      // 24
  unsigned* keys = (unsigned*)(P + 24);
  short* sws = (short*)(keys + 8);
  short* xb = sws;                 // NE (n-major bf16)
  short* xTb = sws + NE;           // NE (d-major bf16)
  short* eTT = sws + 2 * NE;       // NE (d-major)
  short* eST = sws + 3 * NE;       // NE (d-major)
  short* Fb = sws + 4 * NE;        // B*D*D
  short* Mtb = Fb + (size_t)BATCH * C1_b;   // B*D*D
  short* c1b = Mtb + (size_t)BATCH * C1_b;  // B*D*D

  k_prep<<<dim3(4, 8, BATCH), 256, 0, stream>>>(x, xb, xTb, xT, keys);
  // c1 = x^T x / N  (K=512, store + max)
  k_gemm<512, 0><<<dim3(BATCH, 4, 4), 256, 0, stream>>>(
      xTb, NE_b, NN, xTb, NE_b, NN, (void*)c1b, C1_b, DD, 1.0f / NN, keys + 0,
      nullptr, 0);
  // max(c2) only (upper triangle)
  k_c2max<<<dim3(BATCH, 8, 8), 256, 0, stream>>>(xb, keys + 1);
  k_misc<<<2081, 256, 0, stream>>>(c1b, xb, s1, S, a0p, a1p, a2p, a3p, rhop, P, keys);

  // k = 0 T-half: rank-1 shortcut fused into tsm<1>
  k_tsm<1><<<dim3(BATCH, 8), 512, 0, stream>>>(yT, xT, S, s1, log_tT, eTT, P, 0);

  for (int k = 0; k < NUMK; ++k) {
    if (k > 0) {
      // T-half: gw = x @ M(eS)
      k_gemm<512, 1><<<dim3(BATCH, 4, 4), 256, 0, stream>>>(
          xTb, NE_b, NN, eST, NE_b, NN, (void*)Fb, C1_b, DD, 1.0f, nullptr, nullptr, 0);
      k_gemm<256, 2><<<dim3(BATCH, 4, 4), 256, 0, stream>>>(
          Fb, C1_b, DD, c1b, C1_b, DD, (void*)Mtb, C1_b, DD, 0.f, nullptr, P, k);
      k_ygemm<2, 0><<<dim3(BATCH, 8, 4), 256, 0, stream>>>(
          xb, Mtb, xT, zT, log_sT, yT, P, k);
      k_tsm<0><<<dim3(BATCH, 8), 512, 0, stream>>>(yT, xT, S, s1, log_tT, eTT, P, k);
    }
    if (k == NUMK - 1) break;  // tail-trim: last S-half never affects output
    // S-half: gw2 = x @ M(eT)
    k_gemm<512, 1><<<dim3(BATCH, 4, 4), 256, 0, stream>>>(
        xTb, NE_b, NN, eTT, NE_b, NN, (void*)Fb, C1_b, DD, 1.0f, nullptr, nullptr, 0);
    k_gemm<256, 2><<<dim3(BATCH, 4, 4), 256, 0, stream>>>(
        Fb, C1_b, DD, c1b, C1_b, DD, (void*)Mtb, C1_b, DD, 0.f, nullptr, P, k);
    if (k == 0)
      k_ygemm<3, 1><<<dim3(BATCH, 8, 4), 256, 0, stream>>>(
          xb, Mtb, xT, zT, log_tT, yT, P, k);
    else
      k_ygemm<3, 0><<<dim3(BATCH, 8, 4), 256, 0, stream>>>(
          xb, Mtb, xT, zT, log_tT, yT, P, k);
    if (k == 0)
      k_ssm<1><<<dim3(BATCH, 8), 256, 0, stream>>>(yT, eTT, log_sT, eST, zT, P, k);
    else
      k_ssm<0><<<dim3(BATCH, 8), 256, 0, stream>>>(yT, eTT, log_sT, eST, zT, P, k);
  }
  k_out<<<dim3(BATCH, 8), 256, 0, stream>>>(xT, log_tT, out);
}

// Round 9
// 303.886 us; speedup vs baseline: 1.0825x; 1.0825x over previous
//
#include <hip/hip_runtime.h>
#include <math.h>

#define BATCH 32
#define NN 512
#define DD 256
#define NUMK 4

typedef __attribute__((ext_vector_type(8))) short bf16x8;
typedef __attribute__((ext_vector_type(4))) float f32x4;
typedef __attribute__((ext_vector_type(4))) unsigned short u16x4;

__device__ __forceinline__ float softplusf(float v) { return log1pf(expf(v)); }

__device__ __forceinline__ unsigned enc_key(float v) {
  unsigned u = __float_as_uint(v);
  return (u & 0x80000000u) ? ~u : (u | 0x80000000u);
}
__device__ __forceinline__ float dec_key(unsigned k) {
  return (k & 0x80000000u) ? __uint_as_float(k & 0x7fffffffu) : __uint_as_float(~k);
}
__device__ __forceinline__ unsigned short f2b(float f) {
  unsigned u = __float_as_uint(f);
  unsigned r = (u + 0x7fffu + ((u >> 16) & 1u)) >> 16;
  return (unsigned short)r;
}
__device__ __forceinline__ float b2f(unsigned short h) {
  return __uint_as_float(((unsigned)h) << 16);
}

#define GLDS(gp, lp)                                                   \
  __builtin_amdgcn_global_load_lds(                                    \
      (__attribute__((address_space(1))) void*)(void*)(gp),            \
      (__attribute__((address_space(3))) void*)(lp), 16, 0, 0)

// ---------- prep: xb=bf16(x)[n][d], xTb=bf16(x^T)[d][n], xT=f32(x^T); zero keys ----------
__global__ __launch_bounds__(256) void k_prep(const float* __restrict__ x,
                                              short* __restrict__ xb,
                                              short* __restrict__ xTb,
                                              float* __restrict__ xT,
                                              unsigned* keys) {
  __shared__ float t[64][65];
  int b = blockIdx.z, n0 = blockIdx.y * 64, d0 = blockIdx.x * 64;
  if (blockIdx.x == 0 && blockIdx.y == 0 && blockIdx.z == 0 && threadIdx.x == 0) {
    keys[0] = 0u; keys[1] = 0u;
  }
  const float* X = x + (size_t)b * NN * DD;
  int col = threadIdx.x & 63, rr = threadIdx.x >> 6;
#pragma unroll
  for (int s = 0; s < 16; ++s) {
    int row = s * 4 + rr;
    float v = X[(size_t)(n0 + row) * DD + d0 + col];
    t[row][col] = v;
    xb[(size_t)b * NN * DD + (size_t)(n0 + row) * DD + d0 + col] = (short)f2b(v);
  }
  __syncthreads();
#pragma unroll
  for (int s = 0; s < 16; ++s) {
    int row = s * 4 + rr;  // d within tile
    float v = t[col][row];
    size_t idx = (size_t)b * DD * NN + (size_t)(d0 + row) * NN + n0 + col;
    xTb[idx] = (short)f2b(v);
    xT[idx] = v;
  }
}

// ---------- GEMM: C[m][c] = sum_k A[m][k]*B[c][k]; 64x64 tile, BK=64, swizzled LDS ----------
// OUTK 0: bf16 transposed store out[c*ldo+m], *scale, fused atomicMax   (c1 Gram)
// OUTK 1: bf16 natural store out[m*ldo+c]                               (F = x^T @ E)
// OUTK 2: bf16 transposed store, scale = P[4+kiter]/DD                  (Mt = (F@c1)^T)
template <int K, int OUTK>
__global__ __launch_bounds__(256) void k_gemm(
    const short* __restrict__ A, size_t sA, int lda,
    const short* __restrict__ Bp, size_t sB, int ldb,
    void* __restrict__ outp, size_t sO, int ldo,
    float scale, unsigned* maxslot, const float* __restrict__ P, int kiter) {
  __shared__ short As[64 * 64];
  __shared__ short Bs[64 * 64];
  const int b = blockIdx.x;
  const int m0 = blockIdx.y * 64, n0 = blockIdx.z * 64;
  const int tid = threadIdx.x, wave = tid >> 6, lane = tid & 63;
  const int ln = lane & 15, kg = lane >> 4;
  const int wr = (wave >> 1) * 32, wc = (wave & 1) * 32;
  const short* Ab = A + (size_t)b * sA;
  const short* Bb = Bp + (size_t)b * sB;
  const int srow = lane >> 3;
  const int sslot = lane & 7;

  f32x4 acc[2][2];
#pragma unroll
  for (int i = 0; i < 2; ++i)
#pragma unroll
    for (int j = 0; j < 2; ++j) acc[i][j] = (f32x4){0.f, 0.f, 0.f, 0.f};

  for (int k0 = 0; k0 < K; k0 += 64) {
    __syncthreads();
#pragma unroll
    for (int p = 0; p < 2; ++p) {
      int row = p * 32 + wave * 8 + srow;
      int sg = sslot ^ (row & 7);
      GLDS(Ab + (size_t)(m0 + row) * lda + k0 + sg * 8, &As[(p * 32 + wave * 8) * 64]);
      GLDS(Bb + (size_t)(n0 + row) * ldb + k0 + sg * 8, &Bs[(p * 32 + wave * 8) * 64]);
    }
    __syncthreads();
    bf16x8 af[2][2], bfr[2][2];
#pragma unroll
    for (int i = 0; i < 2; ++i)
#pragma unroll
      for (int kk = 0; kk < 2; ++kk) {
        int rowA = wr + i * 16 + ln;
        af[i][kk] = *(const bf16x8*)&As[rowA * 64 + (((kk * 4 + kg) ^ (rowA & 7)) * 8)];
        int rowB = wc + i * 16 + ln;
        bfr[i][kk] = *(const bf16x8*)&Bs[rowB * 64 + (((kk * 4 + kg) ^ (rowB & 7)) * 8)];
      }
#pragma unroll
    for (int kk = 0; kk < 2; ++kk)
#pragma unroll
      for (int i = 0; i < 2; ++i)
#pragma unroll
        for (int j = 0; j < 2; ++j)
          acc[i][j] = __builtin_amdgcn_mfma_f32_16x16x32_bf16(af[i][kk], bfr[j][kk],
                                                              acc[i][j], 0, 0, 0);
  }

  unsigned short* ot = (unsigned short*)outp + (size_t)b * sO;
  if (OUTK == 0 || OUTK == 2) {
    float sc = (OUTK == 2) ? P[4 + kiter] * (1.0f / DD) : scale;
    float tmax = -1e30f;
#pragma unroll
    for (int i = 0; i < 2; ++i) {
      int r = m0 + wr + i * 16 + kg * 4;
#pragma unroll
      for (int j = 0; j < 2; ++j) {
        int c = n0 + wc + j * 16 + ln;
        u16x4 pk;
#pragma unroll
        for (int q = 0; q < 4; ++q) {
          float v = acc[i][j][q] * sc;
          if (OUTK == 0) tmax = fmaxf(tmax, v);
          pk[q] = f2b(v);
        }
        *(u16x4*)&ot[(size_t)c * ldo + r] = pk;
      }
    }
    if (OUTK == 0) {
#pragma unroll
      for (int o = 32; o > 0; o >>= 1) tmax = fmaxf(tmax, __shfl_xor(tmax, o));
      __syncthreads();
      float* smf = (float*)As;
      if (lane == 0) smf[wave] = tmax;
      __syncthreads();
      if (tid == 0)
        atomicMax(maxslot, enc_key(fmaxf(fmaxf(smf[0], smf[1]), fmaxf(smf[2], smf[3]))));
    }
  } else {
#pragma unroll
    for (int i = 0; i < 2; ++i)
#pragma unroll
      for (int j = 0; j < 2; ++j) {
        int c = n0 + wc + j * 16 + ln;
#pragma unroll
        for (int q = 0; q < 4; ++q) {
          int r = m0 + wr + i * 16 + kg * 4 + q;
          ot[(size_t)r * ldo + c] = f2b(acc[i][j][q]);
        }
      }
  }
}

// ---------- c2 max only (no store): upper-triangle blocks of x x^T / D ----------
__global__ __launch_bounds__(256) void k_c2max(const short* __restrict__ xb,
                                               unsigned* maxslot) {
  if (blockIdx.y > blockIdx.z) return;
  __shared__ short As[64 * 64];
  __shared__ short Bs[64 * 64];
  const int b = blockIdx.x;
  const int m0 = blockIdx.y * 64, n0 = blockIdx.z * 64;
  const int tid = threadIdx.x, wave = tid >> 6, lane = tid & 63;
  const int ln = lane & 15, kg = lane >> 4;
  const int wr = (wave >> 1) * 32, wc = (wave & 1) * 32;
  const short* Ab = xb + (size_t)b * ((size_t)NN * DD);
  const int srow = lane >> 3;
  const int sslot = lane & 7;

  f32x4 acc[2][2];
#pragma unroll
  for (int i = 0; i < 2; ++i)
#pragma unroll
    for (int j = 0; j < 2; ++j) acc[i][j] = (f32x4){0.f, 0.f, 0.f, 0.f};

  for (int k0 = 0; k0 < DD; k0 += 64) {
    __syncthreads();
#pragma unroll
    for (int p = 0; p < 2; ++p) {
      int row = p * 32 + wave * 8 + srow;
      int sg = sslot ^ (row & 7);
      GLDS(Ab + (size_t)(m0 + row) * DD + k0 + sg * 8, &As[(p * 32 + wave * 8) * 64]);
      GLDS(Ab + (size_t)(n0 + row) * DD + k0 + sg * 8, &Bs[(p * 32 + wave * 8) * 64]);
    }
    __syncthreads();
    bf16x8 af[2][2], bfr[2][2];
#pragma unroll
    for (int i = 0; i < 2; ++i)
#pragma unroll
      for (int kk = 0; kk < 2; ++kk) {
        int rowA = wr + i * 16 + ln;
        af[i][kk] = *(const bf16x8*)&As[rowA * 64 + (((kk * 4 + kg) ^ (rowA & 7)) * 8)];
        int rowB = wc + i * 16 + ln;
        bfr[i][kk] = *(const bf16x8*)&Bs[rowB * 64 + (((kk * 4 + kg) ^ (rowB & 7)) * 8)];
      }
#pragma unroll
    for (int kk = 0; kk < 2; ++kk)
#pragma unroll
      for (int i = 0; i < 2; ++i)
#pragma unroll
        for (int j = 0; j < 2; ++j)
          acc[i][j] = __builtin_amdgcn_mfma_f32_16x16x32_bf16(af[i][kk], bfr[j][kk],
                                                              acc[i][j], 0, 0, 0);
  }
  float tmax = -1e30f;
#pragma unroll
  for (int i = 0; i < 2; ++i)
#pragma unroll
    for (int j = 0; j < 2; ++j)
#pragma unroll
      for (int q = 0; q < 4; ++q) tmax = fmaxf(tmax, acc[i][j][q] * (1.0f / DD));
#pragma unroll
  for (int o = 32; o > 0; o >>= 1) tmax = fmaxf(tmax, __shfl_xor(tmax, o));
  __syncthreads();
  float* smf = (float*)As;
  if (lane == 0) smf[wave] = tmax;
  __syncthreads();
  if (tid == 0)
    atomicMax(maxslot, enc_key(fmaxf(fmaxf(smf[0], smf[1]), fmaxf(smf[2], smf[3]))));
}

// ---------- y-GEMM: y = x @ Mt^T with fused affine epilogue; d-major f32x4 store ----------
// MODE 2 (T-half, k>=1): yT = (xT + acc + z + rho*(eta_{k-1} + y2T - lse_s[d]))/(rho+a0)
// MODE 3 (S-half):       y2T = (acc - z + rho*(mu_k + yT - lse_t[n]))/rho
template <int MODE, int ZFIRST>
__global__ __launch_bounds__(256) void k_ygemm(
    const short* __restrict__ xb, const short* __restrict__ Mt,
    const float* __restrict__ xT, const short* __restrict__ zb,
    const float* __restrict__ aux, const float* __restrict__ lseV,
    float* __restrict__ outT, const float* __restrict__ P, int kiter) {
  __shared__ short As[64 * 64];
  __shared__ short Bs[64 * 64];
  const int b = blockIdx.x;
  const int m0 = blockIdx.y * 64;  // n
  const int n0 = blockIdx.z * 64;  // d
  const int tid = threadIdx.x, wave = tid >> 6, lane = tid & 63;
  const int ln = lane & 15, kg = lane >> 4;
  const int wr = (wave >> 1) * 32, wc = (wave & 1) * 32;
  const short* Ab = xb + (size_t)b * ((size_t)NN * DD);
  const short* Bb = Mt + (size_t)b * ((size_t)DD * DD);
  const size_t base = (size_t)b * ((size_t)NN * DD);
  const int srow = lane >> 3;
  const int sslot = lane & 7;

  f32x4 acc[2][2];
#pragma unroll
  for (int i = 0; i < 2; ++i)
#pragma unroll
    for (int j = 0; j < 2; ++j) acc[i][j] = (f32x4){0.f, 0.f, 0.f, 0.f};

  for (int k0 = 0; k0 < DD; k0 += 64) {
    __syncthreads();
#pragma unroll
    for (int p = 0; p < 2; ++p) {
      int row = p * 32 + wave * 8 + srow;
      int sg = sslot ^ (row & 7);
      GLDS(Ab + (size_t)(m0 + row) * DD + k0 + sg * 8, &As[(p * 32 + wave * 8) * 64]);
      GLDS(Bb + (size_t)(n0 + row) * DD + k0 + sg * 8, &Bs[(p * 32 + wave * 8) * 64]);
    }
    __syncthreads();
    bf16x8 af[2][2], bfr[2][2];
#pragma unroll
    for (int i = 0; i < 2; ++i)
#pragma unroll
      for (int kk = 0; kk < 2; ++kk) {
        int rowA = wr + i * 16 + ln;
        af[i][kk] = *(const bf16x8*)&As[rowA * 64 + (((kk * 4 + kg) ^ (rowA & 7)) * 8)];
        int rowB = wc + i * 16 + ln;
        bfr[i][kk] = *(const bf16x8*)&Bs[rowB * 64 + (((kk * 4 + kg) ^ (rowB & 7)) * 8)];
      }
#pragma unroll
    for (int kk = 0; kk < 2; ++kk)
#pragma unroll
      for (int i = 0; i < 2; ++i)
#pragma unroll
        for (int j = 0; j < 2; ++j)
          acc[i][j] = __builtin_amdgcn_mfma_f32_16x16x32_bf16(af[i][kk], bfr[j][kk],
                                                              acc[i][j], 0, 0, 0);
  }

  const float a0 = P[kiter], rho = P[8 + kiter];
  const float inv = (MODE == 2) ? 1.0f / (rho + a0) : 1.0f / rho;
  const float sh = (MODE == 2) ? P[16 + kiter - 1] : P[12 + kiter];
#pragma unroll
  for (int i = 0; i < 2; ++i)
#pragma unroll
    for (int j = 0; j < 2; ++j) {
      int cd = n0 + wc + j * 16 + ln;            // d row
      int rn = m0 + wr + i * 16 + kg * 4;        // 4 consecutive n
      size_t idx = base + (size_t)cd * NN + rn;
      f32x4 av = *(const f32x4*)&aux[idx];
      u16x4 zv4;
      if (!ZFIRST) zv4 = *(const u16x4*)&zb[idx];
      f32x4 o;
      if (MODE == 2) {
        float lse = lseV[(size_t)b * DD + cd];
        f32x4 xv = *(const f32x4*)&xT[idx];
#pragma unroll
        for (int q = 0; q < 4; ++q) {
          float zf = ZFIRST ? 0.0f : b2f(zv4[q]);
          o[q] = (xv[q] + acc[i][j][q] + zf + rho * (sh + av[q] - lse)) * inv;
        }
      } else {
        f32x4 lt = *(const f32x4*)&lseV[(size_t)b * NN + rn];
#pragma unroll
        for (int q = 0; q < 4; ++q) {
          float zf = ZFIRST ? 0.0f : b2f(zv4[q]);
          o[q] = (acc[i][j][q] - zf + rho * (sh + av[q] - lt[q])) * inv;
        }
      }
      *(f32x4*)&outT[idx] = o;
    }
}

// ---------- misc: s1 = rowsum(c1b), S = colsum(xb), scalar params ----------
__global__ __launch_bounds__(256) void k_misc(const short* __restrict__ c1b,
                                              const short* __restrict__ xb,
                                              float* __restrict__ s1,
                                              float* __restrict__ S,
                                              const float* a0p, const float* a1p,
                                              const float* a2p, const float* a3p,
                                              const float* rhop, float* P,
                                              const unsigned* keys) {
  int bid = blockIdx.x;
  int lane = threadIdx.x & 63;
  if (bid < 2048) {
    int row = bid * 4 + (threadIdx.x >> 6);
    u16x4 v = *(const u16x4*)(c1b + (size_t)row * 256 + lane * 4);
    float s = 0.f;
#pragma unroll
    for (int q = 0; q < 4; ++q) s += b2f(v[q]);
#pragma unroll
    for (int o = 32; o > 0; o >>= 1) s += __shfl_xor(s, o);
    if (lane == 0) s1[row] = s;
  } else if (bid < 2080) {
    int b = bid - 2048;
    int d = threadIdx.x;
    const short* X = xb + (size_t)b * NN * DD;
    float s = 0.f;
    for (int n = 0; n < NN; ++n) s += b2f((unsigned short)X[(size_t)n * DD + d]);
    S[(size_t)b * DD + d] = s;
  } else if (threadIdx.x == 0) {
    float M1 = dec_key(keys[0]);
    float M2 = dec_key(keys[1]);
    float lq0 = logf(1.0f / NN + 1e-8f);
    float lp0 = logf(1.0f / DD + 1e-8f);
    float mu = lq0, eta = lp0, z1 = 0.f, z2 = 0.f;
    for (int k = 0; k < NUMK; ++k) {
      float a0 = softplusf(a0p[k]), a1 = softplusf(a1p[k]);
      float a2 = softplusf(a2p[k]), a3 = softplusf(a3p[k]);
      float rho = softplusf(rhop[k]);
      P[0 + k] = a0;
      P[4 + k] = a1 / (M1 * M2);
      P[8 + k] = rho;
      P[12 + k] = mu;
      P[16 + k] = eta;
      float t1 = mu;
      mu = (a2 * lq0 + rho * t1 - z1) / (a2 + rho);
      z1 += rho * (expf(mu) - expf(t1));
      float s1v = eta;
      eta = (a3 * lp0 + rho * s1v - z2) / (a3 + rho);
      z2 += rho * (expf(eta) - expf(s1v));
    }
  }
}

// ---------- T-softmax (axis=d): compute lse_t + eTT (no log field) ----------
// FIRST: y built inline from xT + rank-1 gw; also writes yT (S-half needs it).
// LAST: skip eTT (dead after final T-update).
template <int FIRST, int LAST>
__global__ __launch_bounds__(512) void k_tsm(
    float* __restrict__ yT, const float* __restrict__ xT,
    const float* __restrict__ S, const float* __restrict__ s1,
    float* __restrict__ lse_t, short* __restrict__ eTT,
    const float* __restrict__ P, int kiter) {
  const int b = blockIdx.x, n0 = blockIdx.y * 64;
  const int nl = threadIdx.x >> 3, ds = threadIdx.x & 7;
  const int n = n0 + nl;
  const size_t base = (size_t)b * ((size_t)NN * DD);
  float y[32];
  float m = -1e30f;
  if (FIRST) {
    float dot = 0.f;
#pragma unroll
    for (int dk = 0; dk < 32; ++dk) {
      int d = dk * 8 + ds;
      float v = xT[base + (size_t)d * NN + n];
      y[dk] = v;
      dot += v * S[(size_t)b * DD + d];
    }
    dot += __shfl_xor(dot, 1);
    dot += __shfl_xor(dot, 2);
    dot += __shfl_xor(dot, 4);
    const float c0 = logf(1.0f / NN + 1e-8f) + logf(1.0f / DD + 1e-8f);
    float g = P[4] * expf(c0) * dot * (1.0f / DD);
    float inv = 1.0f / (P[8] + P[0]);
#pragma unroll
    for (int dk = 0; dk < 32; ++dk) {
      int d = dk * 8 + ds;
      y[dk] = (y[dk] + g * s1[(size_t)b * DD + d]) * inv;
      m = fmaxf(m, y[dk]);
    }
  } else {
#pragma unroll
    for (int dk = 0; dk < 32; ++dk) {
      int d = dk * 8 + ds;
      float v = yT[base + (size_t)d * NN + n];
      y[dk] = v;
      m = fmaxf(m, v);
    }
  }
  m = fmaxf(m, __shfl_xor(m, 1));
  m = fmaxf(m, __shfl_xor(m, 2));
  m = fmaxf(m, __shfl_xor(m, 4));
  float s = 0.f;
#pragma unroll
  for (int dk = 0; dk < 32; ++dk) s += expf(y[dk] - m);
  s += __shfl_xor(s, 1);
  s += __shfl_xor(s, 2);
  s += __shfl_xor(s, 4);
  const float lse = m + logf(s);
  if (ds == 0) lse_t[(size_t)b * NN + n] = lse;
  const float mu = P[12 + kiter];
#pragma unroll
  for (int dk = 0; dk < 32; ++dk) {
    int d = dk * 8 + ds;
    size_t idx = base + (size_t)d * NN + n;
    if (FIRST) yT[idx] = y[dk];
    if (!LAST) eTT[idx] = (short)f2b(expf(mu + y[dk] - lse));
  }
}

// ---------- S-softmax (axis=n): lse_s + eS bf16 + dual z-update (z bf16) ----------
template <int ZFIRST>
__global__ __launch_bounds__(256) void k_ssm(
    const float* __restrict__ y2T, const short* __restrict__ eTT,
    float* __restrict__ lse_sV, short* __restrict__ eST, short* __restrict__ zb,
    const float* __restrict__ P, int kiter) {
  const int b = blockIdx.x, d0 = blockIdx.y * 32;
  const int wave = threadIdx.x >> 6, lane = threadIdx.x & 63;
  const size_t base = (size_t)b * ((size_t)NN * DD);
  const float rho = P[8 + kiter], eta = P[16 + kiter];
#pragma unroll
  for (int rr = 0; rr < 8; ++rr) {
    int row = d0 + wave * 8 + rr;
    size_t roff = base + (size_t)row * NN + lane * 8;
    f32x4 v0 = *(const f32x4*)&y2T[roff];
    f32x4 v1 = *(const f32x4*)&y2T[roff + 4];
    float m = fmaxf(fmaxf(fmaxf(v0[0], v0[1]), fmaxf(v0[2], v0[3])),
                    fmaxf(fmaxf(v1[0], v1[1]), fmaxf(v1[2], v1[3])));
#pragma unroll
    for (int o = 1; o < 64; o <<= 1) m = fmaxf(m, __shfl_xor(m, o));
    float s = 0.f;
#pragma unroll
    for (int q = 0; q < 4; ++q) s += expf(v0[q] - m) + expf(v1[q] - m);
#pragma unroll
    for (int o = 1; o < 64; o <<= 1) s += __shfl_xor(s, o);
    float lse = m + logf(s);
    if (lane == 0) lse_sV[(size_t)b * DD + row] = lse;
    f32x4 es0, es1;
    u16x4 ev0, ev1;
#pragma unroll
    for (int q = 0; q < 4; ++q) {
      es0[q] = expf(eta + v0[q] - lse);
      ev0[q] = f2b(es0[q]);
      es1[q] = expf(eta + v1[q] - lse);
      ev1[q] = f2b(es1[q]);
    }
    *(u16x4*)&eST[roff] = ev0;
    *(u16x4*)&eST[roff + 4] = ev1;
    bf16x8 et = *(const bf16x8*)&eTT[roff];
    u16x4 z0, z1;
    if (!ZFIRST) {
      z0 = *(const u16x4*)&zb[roff];
      z1 = *(const u16x4*)&zb[roff + 4];
    }
    u16x4 zo0, zo1;
#pragma unroll
    for (int q = 0; q < 4; ++q) {
      float zf0 = ZFIRST ? 0.0f : b2f(z0[q]);
      float zf1 = ZFIRST ? 0.0f : b2f(z1[q]);
      zo0[q] = f2b(zf0 + rho * (b2f((unsigned short)et[q]) - es0[q]));
      zo1[q] = f2b(zf1 + rho * (b2f((unsigned short)et[4 + q]) - es1[q]));
    }
    *(u16x4*)&zb[roff] = zo0;
    *(u16x4*)&zb[roff + 4] = zo1;
  }
}

// ---------- output: out[b][d'] = D * sum_n xT * exp(mu3 + yT - lse_t[n]) ----------
__global__ __launch_bounds__(256) void k_out(const float* __restrict__ xT,
                                             const float* __restrict__ yT,
                                             const float* __restrict__ lse_t,
                                             float* __restrict__ out,
                                             const float* __restrict__ P) {
  const int b = blockIdx.x, d0 = blockIdx.y * 32;
  const int wave = threadIdx.x >> 6, lane = threadIdx.x & 63;
  const size_t base = (size_t)b * ((size_t)NN * DD);
  const float mu = P[15];
  f32x4 l0 = *(const f32x4*)&lse_t[(size_t)b * NN + lane * 8];
  f32x4 l1 = *(const f32x4*)&lse_t[(size_t)b * NN + lane * 8 + 4];
#pragma unroll
  for (int rr = 0; rr < 8; ++rr) {
    int row = d0 + wave * 8 + rr;
    size_t roff = base + (size_t)row * NN + lane * 8;
    f32x4 x0 = *(const f32x4*)&xT[roff];
    f32x4 x1 = *(const f32x4*)&xT[roff + 4];
    f32x4 y0 = *(const f32x4*)&yT[roff];
    f32x4 y1 = *(const f32x4*)&yT[roff + 4];
    float acc = 0.f;
#pragma unroll
    for (int q = 0; q < 4; ++q)
      acc += x0[q] * expf(mu + y0[q] - l0[q]) + x1[q] * expf(mu + y1[q] - l1[q]);
#pragma unroll
    for (int o = 1; o < 64; o <<= 1) acc += __shfl_xor(acc, o);
    if (lane == 0) out[(size_t)b * DD + row] = (float)DD * acc;
  }
}

// ---------- launch ----------
extern "C" void kernel_launch(void* const* d_in, const int* in_sizes, int n_in,
                              void* d_out, int out_size, void* d_ws, size_t ws_size,
                              hipStream_t stream) {
  const float* x = (const float*)d_in[0];
  const float* a0p = (const float*)d_in[1];
  const float* a1p = (const float*)d_in[2];
  const float* a2p = (const float*)d_in[3];
  const float* a3p = (const float*)d_in[4];
  const float* rhop = (const float*)d_in[5];
  float* out = (float*)d_out;

  const size_t NE = (size_t)BATCH * NN * DD;
  const size_t NE_b = (size_t)NN * DD;
  const size_t C1_b = (size_t)DD * DD;

  float* fws = (float*)d_ws;
  float* xT = fws;                 // NE
  float* yT = fws + NE;            // NE (T-half y, d-major)
  float* y2T = fws + 2 * NE;       // NE (S-half y2, d-major)
  float* S = fws + 3 * NE;         // B*D colsum(x)
  float* s1 = S + BATCH * DD;      // B*D rowsum(c1)
  float* lse_t = s1 + BATCH * DD;  // B*N
  float* lse_s = lse_t + BATCH * NN;  // B*D
  float* P = lse_s + BATCH * DD;   // 24
  unsigned* keys = (unsigned*)(P + 24);
  short* sws = (short*)(keys + 8);
  short* xb = sws;                 // NE (n-major bf16)
  short* xTb = sws + NE;           // NE (d-major bf16)
  short* eTT = sws + 2 * NE;       // NE (d-major)
  short* eST = sws + 3 * NE;       // NE (d-major)
  short* zb = sws + 4 * NE;        // NE (d-major bf16 dual)
  short* Fb = sws + 5 * NE;        // B*D*D
  short* Mtb = Fb + (size_t)BATCH * C1_b;   // B*D*D
  short* c1b = Mtb + (size_t)BATCH * C1_b;  // B*D*D

  k_prep<<<dim3(4, 8, BATCH), 256, 0, stream>>>(x, xb, xTb, xT, keys);
  k_gemm<512, 0><<<dim3(BATCH, 4, 4), 256, 0, stream>>>(
      xTb, NE_b, NN, xTb, NE_b, NN, (void*)c1b, C1_b, DD, 1.0f / NN, keys + 0,
      nullptr, 0);
  k_c2max<<<dim3(BATCH, 8, 8), 256, 0, stream>>>(xb, keys + 1);
  k_misc<<<2081, 256, 0, stream>>>(c1b, xb, s1, S, a0p, a1p, a2p, a3p, rhop, P, keys);

  // k = 0 T-half: rank-1 shortcut; writes yT + lse_t + eTT
  k_tsm<1, 0><<<dim3(BATCH, 8), 512, 0, stream>>>(yT, xT, S, s1, lse_t, eTT, P, 0);

  for (int k = 0; k < NUMK; ++k) {
    if (k > 0) {
      // T-half: gw = x @ M(eS);  y -> yT; softmax -> lse_t, eTT
      k_gemm<512, 1><<<dim3(BATCH, 4, 4), 256, 0, stream>>>(
          xTb, NE_b, NN, eST, NE_b, NN, (void*)Fb, C1_b, DD, 1.0f, nullptr, nullptr, 0);
      k_gemm<256, 2><<<dim3(BATCH, 4, 4), 256, 0, stream>>>(
          Fb, C1_b, DD, c1b, C1_b, DD, (void*)Mtb, C1_b, DD, 0.f, nullptr, P, k);
      k_ygemm<2, 0><<<dim3(BATCH, 8, 4), 256, 0, stream>>>(
          xb, Mtb, xT, zb, y2T, lse_s, yT, P, k);
      if (k == NUMK - 1)
        k_tsm<0, 1><<<dim3(BATCH, 8), 512, 0, stream>>>(yT, xT, S, s1, lse_t, eTT, P, k);
      else
        k_tsm<0, 0><<<dim3(BATCH, 8), 512, 0, stream>>>(yT, xT, S, s1, lse_t, eTT, P, k);
    }
    if (k == NUMK - 1) break;  // tail-trim: last S-half never affects output
    // S-half: gw2 = x @ M(eT); y2 -> y2T; softmax -> lse_s, eST; z-update
    k_gemm<512, 1><<<dim3(BATCH, 4, 4), 256, 0, stream>>>(
        xTb, NE_b, NN, eTT, NE_b, NN, (void*)Fb, C1_b, DD, 1.0f, nullptr, nullptr, 0);
    k_gemm<256, 2><<<dim3(BATCH, 4, 4), 256, 0, stream>>>(
        Fb, C1_b, DD, c1b, C1_b, DD, (void*)Mtb, C1_b, DD, 0.f, nullptr, P, k);
    if (k == 0)
      k_ygemm<3, 1><<<dim3(BATCH, 8, 4), 256, 0, stream>>>(
          xb, Mtb, xT, zb, yT, lse_t, y2T, P, k);
    else
      k_ygemm<3, 0><<<dim3(BATCH, 8, 4), 256, 0, stream>>>(
          xb, Mtb, xT, zb, yT, lse_t, y2T, P, k);
    if (k == 0)
      k_ssm<1><<<dim3(BATCH, 8), 256, 0, stream>>>(y2T, eTT, lse_s, eST, zb, P, k);
    else
      k_ssm<0><<<dim3(BATCH, 8), 256, 0, stream>>>(y2T, eTT, lse_s, eST, zb, P, k);
  }
  k_out<<<dim3(BATCH, 8), 256, 0, stream>>>(xT, yT, lse_t, out, P);
}

// Round 10
// 246.541 us; speedup vs baseline: 1.3343x; 1.2326x over previous
//
#include <hip/hip_runtime.h>
#include <math.h>

#define BATCH 32
#define NN 512
#define DD 256
#define NUMK 4

typedef __attribute__((ext_vector_type(8))) short bf16x8;
typedef __attribute__((ext_vector_type(4))) float f32x4;
typedef __attribute__((ext_vector_type(4))) unsigned short u16x4;

__device__ __forceinline__ float softplusf(float v) { return log1pf(expf(v)); }

__device__ __forceinline__ unsigned enc_key(float v) {
  unsigned u = __float_as_uint(v);
  return (u & 0x80000000u) ? ~u : (u | 0x80000000u);
}
__device__ __forceinline__ float dec_key(unsigned k) {
  return (k & 0x80000000u) ? __uint_as_float(k & 0x7fffffffu) : __uint_as_float(~k);
}
__device__ __forceinline__ unsigned short f2b(float f) {
  unsigned u = __float_as_uint(f);
  unsigned r = (u + 0x7fffu + ((u >> 16) & 1u)) >> 16;
  return (unsigned short)r;
}
__device__ __forceinline__ float b2f(unsigned short h) {
  return __uint_as_float(((unsigned)h) << 16);
}

#define GLDS(gp, lp)                                                   \
  __builtin_amdgcn_global_load_lds(                                    \
      (__attribute__((address_space(1))) void*)(void*)(gp),            \
      (__attribute__((address_space(3))) void*)(lp), 16, 0, 0)

// ---------- prep: xb=bf16(x)[n][d], xTb=bf16(x^T)[d][n]; zero keys ----------
__global__ __launch_bounds__(256) void k_prep(const float* __restrict__ x,
                                              short* __restrict__ xb,
                                              short* __restrict__ xTb,
                                              unsigned* keys) {
  __shared__ float t[64][65];
  int b = blockIdx.z, n0 = blockIdx.y * 64, d0 = blockIdx.x * 64;
  if (blockIdx.x == 0 && blockIdx.y == 0 && blockIdx.z == 0 && threadIdx.x == 0) {
    keys[0] = 0u; keys[1] = 0u;
  }
  const float* X = x + (size_t)b * NN * DD;
  int col = threadIdx.x & 63, rr = threadIdx.x >> 6;
#pragma unroll
  for (int s = 0; s < 16; ++s) {
    int row = s * 4 + rr;
    float v = X[(size_t)(n0 + row) * DD + d0 + col];
    t[row][col] = v;
    xb[(size_t)b * NN * DD + (size_t)(n0 + row) * DD + d0 + col] = (short)f2b(v);
  }
  __syncthreads();
#pragma unroll
  for (int s = 0; s < 16; ++s) {
    int row = s * 4 + rr;
    xTb[(size_t)b * DD * NN + (size_t)(d0 + row) * NN + n0 + col] = (short)f2b(t[col][row]);
  }
}

// ---------- GEMM: C[m][c] = sum_k A[m][k]*B[c][k]; 64x64 tile, BK=64 ----------
// OUTK 0: bf16 transposed store, *scale, fused atomicMax   (c1 Gram)
// OUTK 1: bf16 natural store                               (F = x^T @ E)
// OUTK 2: bf16 transposed store, scale P[4+k]/DD           (Mt_S)
// OUTK 3: same as 2 plus identity on diagonal              (Mt_T)
template <int K, int OUTK>
__global__ __launch_bounds__(256) void k_gemm(
    const short* __restrict__ A, size_t sA, int lda,
    const short* __restrict__ Bp, size_t sB, int ldb,
    void* __restrict__ outp, size_t sO, int ldo,
    float scale, unsigned* maxslot, const float* __restrict__ P, int kiter) {
  __shared__ short As[64 * 64];
  __shared__ short Bs[64 * 64];
  const int b = blockIdx.x;
  const int m0 = blockIdx.y * 64, n0 = blockIdx.z * 64;
  const int tid = threadIdx.x, wave = tid >> 6, lane = tid & 63;
  const int ln = lane & 15, kg = lane >> 4;
  const int wr = (wave >> 1) * 32, wc = (wave & 1) * 32;
  const short* Ab = A + (size_t)b * sA;
  const short* Bb = Bp + (size_t)b * sB;

  f32x4 acc[2][2];
#pragma unroll
  for (int i = 0; i < 2; ++i)
#pragma unroll
    for (int j = 0; j < 2; ++j) acc[i][j] = (f32x4){0.f, 0.f, 0.f, 0.f};

  for (int k0 = 0; k0 < K; k0 += 64) {
    __syncthreads();
#pragma unroll
    for (int p = 0; p < 2; ++p) {
      int row = p * 32 + wave * 8 + (lane >> 3);
      int sg = (lane & 7) ^ (row & 7);
      GLDS(Ab + (size_t)(m0 + row) * lda + k0 + sg * 8, &As[(p * 32 + wave * 8) * 64]);
      GLDS(Bb + (size_t)(n0 + row) * ldb + k0 + sg * 8, &Bs[(p * 32 + wave * 8) * 64]);
    }
    __syncthreads();
    bf16x8 af[2][2], bfr[2][2];
#pragma unroll
    for (int i = 0; i < 2; ++i)
#pragma unroll
      for (int kk = 0; kk < 2; ++kk) {
        int rowA = wr + i * 16 + ln;
        af[i][kk] = *(const bf16x8*)&As[rowA * 64 + (((kk * 4 + kg) ^ (rowA & 7)) * 8)];
        int rowB = wc + i * 16 + ln;
        bfr[i][kk] = *(const bf16x8*)&Bs[rowB * 64 + (((kk * 4 + kg) ^ (rowB & 7)) * 8)];
      }
#pragma unroll
    for (int kk = 0; kk < 2; ++kk)
#pragma unroll
      for (int i = 0; i < 2; ++i)
#pragma unroll
        for (int j = 0; j < 2; ++j)
          acc[i][j] = __builtin_amdgcn_mfma_f32_16x16x32_bf16(af[i][kk], bfr[j][kk],
                                                              acc[i][j], 0, 0, 0);
  }

  unsigned short* ot = (unsigned short*)outp + (size_t)b * sO;
  if (OUTK != 1) {
    float sc = (OUTK >= 2) ? P[4 + kiter] * (1.0f / DD) : scale;
    float tmax = -1e30f;
#pragma unroll
    for (int i = 0; i < 2; ++i) {
      int r0 = m0 + wr + i * 16 + kg * 4;
#pragma unroll
      for (int j = 0; j < 2; ++j) {
        int c = n0 + wc + j * 16 + ln;
        u16x4 pk;
#pragma unroll
        for (int q = 0; q < 4; ++q) {
          float v = acc[i][j][q] * sc;
          if (OUTK == 3 && c == r0 + q) v += 1.0f;
          if (OUTK == 0) tmax = fmaxf(tmax, v);
          pk[q] = f2b(v);
        }
        *(u16x4*)&ot[(size_t)c * ldo + r0] = pk;
      }
    }
    if (OUTK == 0) {
#pragma unroll
      for (int o = 32; o > 0; o >>= 1) tmax = fmaxf(tmax, __shfl_xor(tmax, o));
      __syncthreads();
      float* smf = (float*)As;
      if (lane == 0) smf[wave] = tmax;
      __syncthreads();
      if (tid == 0)
        atomicMax(maxslot, enc_key(fmaxf(fmaxf(smf[0], smf[1]), fmaxf(smf[2], smf[3]))));
    }
  } else {
#pragma unroll
    for (int i = 0; i < 2; ++i)
#pragma unroll
      for (int j = 0; j < 2; ++j) {
        int c = n0 + wc + j * 16 + ln;
#pragma unroll
        for (int q = 0; q < 4; ++q) {
          int r = m0 + wr + i * 16 + kg * 4 + q;
          ot[(size_t)r * ldo + c] = f2b(acc[i][j][q]);
        }
      }
  }
}

// ---------- c2 max only: upper-triangle blocks of x x^T / D ----------
__global__ __launch_bounds__(256) void k_c2max(const short* __restrict__ xb,
                                               unsigned* maxslot) {
  if (blockIdx.y > blockIdx.z) return;
  __shared__ short As[64 * 64];
  __shared__ short Bs[64 * 64];
  const int b = blockIdx.x;
  const int m0 = blockIdx.y * 64, n0 = blockIdx.z * 64;
  const int tid = threadIdx.x, wave = tid >> 6, lane = tid & 63;
  const int ln = lane & 15, kg = lane >> 4;
  const int wr = (wave >> 1) * 32, wc = (wave & 1) * 32;
  const short* Ab = xb + (size_t)b * ((size_t)NN * DD);

  f32x4 acc[2][2];
#pragma unroll
  for (int i = 0; i < 2; ++i)
#pragma unroll
    for (int j = 0; j < 2; ++j) acc[i][j] = (f32x4){0.f, 0.f, 0.f, 0.f};

  for (int k0 = 0; k0 < DD; k0 += 64) {
    __syncthreads();
#pragma unroll
    for (int p = 0; p < 2; ++p) {
      int row = p * 32 + wave * 8 + (lane >> 3);
      int sg = (lane & 7) ^ (row & 7);
      GLDS(Ab + (size_t)(m0 + row) * DD + k0 + sg * 8, &As[(p * 32 + wave * 8) * 64]);
      GLDS(Ab + (size_t)(n0 + row) * DD + k0 + sg * 8, &Bs[(p * 32 + wave * 8) * 64]);
    }
    __syncthreads();
    bf16x8 af[2][2], bfr[2][2];
#pragma unroll
    for (int i = 0; i < 2; ++i)
#pragma unroll
      for (int kk = 0; kk < 2; ++kk) {
        int rowA = wr + i * 16 + ln;
        af[i][kk] = *(const bf16x8*)&As[rowA * 64 + (((kk * 4 + kg) ^ (rowA & 7)) * 8)];
        int rowB = wc + i * 16 + ln;
        bfr[i][kk] = *(const bf16x8*)&Bs[rowB * 64 + (((kk * 4 + kg) ^ (rowB & 7)) * 8)];
      }
#pragma unroll
    for (int kk = 0; kk < 2; ++kk)
#pragma unroll
      for (int i = 0; i < 2; ++i)
#pragma unroll
        for (int j = 0; j < 2; ++j)
          acc[i][j] = __builtin_amdgcn_mfma_f32_16x16x32_bf16(af[i][kk], bfr[j][kk],
                                                              acc[i][j], 0, 0, 0);
  }
  float tmax = -1e30f;
#pragma unroll
  for (int i = 0; i < 2; ++i)
#pragma unroll
    for (int j = 0; j < 2; ++j)
#pragma unroll
      for (int q = 0; q < 4; ++q) tmax = fmaxf(tmax, acc[i][j][q] * (1.0f / DD));
#pragma unroll
  for (int o = 32; o > 0; o >>= 1) tmax = fmaxf(tmax, __shfl_xor(tmax, o));
  __syncthreads();
  float* smf = (float*)As;
  if (lane == 0) smf[wave] = tmax;
  __syncthreads();
  if (tid == 0)
    atomicMax(maxslot, enc_key(fmaxf(fmaxf(smf[0], smf[1]), fmaxf(smf[2], smf[3]))));
}

// ---------- misc: s1 = rowsum(c1b), S = colsum(xb), scalar params ----------
__global__ __launch_bounds__(256) void k_misc(const short* __restrict__ c1b,
                                              const short* __restrict__ xb,
                                              float* __restrict__ s1,
                                              float* __restrict__ S,
                                              const float* a0p, const float* a1p,
                                              const float* a2p, const float* a3p,
                                              const float* rhop, float* P,
                                              const unsigned* keys) {
  int bid = blockIdx.x;
  int lane = threadIdx.x & 63;
  if (bid < 2048) {
    int row = bid * 4 + (threadIdx.x >> 6);
    u16x4 v = *(const u16x4*)(c1b + (size_t)row * 256 + lane * 4);
    float s = 0.f;
#pragma unroll
    for (int q = 0; q < 4; ++q) s += b2f(v[q]);
#pragma unroll
    for (int o = 32; o > 0; o >>= 1) s += __shfl_xor(s, o);
    if (lane == 0) s1[row] = s;
  } else if (bid < 2080) {
    int b = bid - 2048;
    int d = threadIdx.x;
    const short* X = xb + (size_t)b * NN * DD;
    float s = 0.f;
    for (int n = 0; n < NN; ++n) s += b2f((unsigned short)X[(size_t)n * DD + d]);
    S[(size_t)b * DD + d] = s;
  } else if (threadIdx.x == 0) {
    float M1 = dec_key(keys[0]);
    float M2 = dec_key(keys[1]);
    float lq0 = logf(1.0f / NN + 1e-8f);
    float lp0 = logf(1.0f / DD + 1e-8f);
    float mu = lq0, eta = lp0, z1 = 0.f, z2 = 0.f;
    for (int k = 0; k < NUMK; ++k) {
      float a0 = softplusf(a0p[k]), a1 = softplusf(a1p[k]);
      float a2 = softplusf(a2p[k]), a3 = softplusf(a3p[k]);
      float rho = softplusf(rhop[k]);
      P[0 + k] = a0;
      P[4 + k] = a1 / (M1 * M2);
      P[8 + k] = rho;
      P[12 + k] = mu;
      P[16 + k] = eta;
      float t1 = mu;
      mu = (a2 * lq0 + rho * t1 - z1) / (a2 + rho);
      z1 += rho * (expf(mu) - expf(t1));
      float s1v = eta;
      eta = (a3 * lp0 + rho * s1v - z2) / (a3 + rho);
      z2 += rho * (expf(eta) - expf(s1v));
    }
  }
}

// ---------- k=0 T-half: rank-1 shortcut, writes eTT only ----------
__global__ __launch_bounds__(512) void k_tsm0(
    const short* __restrict__ xTb, const float* __restrict__ S,
    const float* __restrict__ s1, short* __restrict__ eTT,
    const float* __restrict__ P) {
  const int b = blockIdx.x, n0 = blockIdx.y * 64;
  const int nl = threadIdx.x >> 3, ds = threadIdx.x & 7;
  const int n = n0 + nl;
  const size_t base = (size_t)b * ((size_t)NN * DD);
  float y[32];
  float dot = 0.f;
#pragma unroll
  for (int dk = 0; dk < 32; ++dk) {
    int d = dk * 8 + ds;
    float v = b2f((unsigned short)xTb[base + (size_t)d * NN + n]);
    y[dk] = v;
    dot += v * S[(size_t)b * DD + d];
  }
  dot += __shfl_xor(dot, 1);
  dot += __shfl_xor(dot, 2);
  dot += __shfl_xor(dot, 4);
  const float c0 = logf(1.0f / NN + 1e-8f) + logf(1.0f / DD + 1e-8f);
  float g = P[4] * expf(c0) * dot * (1.0f / DD);
  float inv = 1.0f / (P[8] + P[0]);
  float m = -1e30f;
#pragma unroll
  for (int dk = 0; dk < 32; ++dk) {
    int d = dk * 8 + ds;
    y[dk] = (y[dk] + g * s1[(size_t)b * DD + d]) * inv;
    m = fmaxf(m, y[dk]);
  }
  m = fmaxf(m, __shfl_xor(m, 1));
  m = fmaxf(m, __shfl_xor(m, 2));
  m = fmaxf(m, __shfl_xor(m, 4));
  float s = 0.f;
#pragma unroll
  for (int dk = 0; dk < 32; ++dk) s += expf(y[dk] - m);
  s += __shfl_xor(s, 1);
  s += __shfl_xor(s, 2);
  s += __shfl_xor(s, 4);
  const float lse = m + logf(s);
  const float mu = P[12];
#pragma unroll
  for (int dk = 0; dk < 32; ++dk) {
    int d = dk * 8 + ds;
    eTT[base + (size_t)d * NN + n] = (short)f2b(expf(mu + y[dk] - lse));
  }
}

// ---------- fused T-half (k>=1): GEMM(x@Mt_T) + T-softmax(axis=d) ----------
// grid (BATCH, 16): n-tile 32, all 256 d. 4 waves; wave owns d in [w*64,(w+1)*64).
// y = (acc + z + rho*log(eS))/(rho+a0);  acc includes x via identity in Mt.
// LAST: write output partials instead of eTT.
template <int LAST>
__global__ __launch_bounds__(256) void k_ft(
    const short* __restrict__ xb, const short* __restrict__ Mtb,
    const short* __restrict__ eST, const short* __restrict__ zb,
    short* __restrict__ eTT, const short* __restrict__ xTb,
    float* __restrict__ part, const float* __restrict__ P, int kiter) {
  __shared__ short As[32 * 64];   // xb n-tile
  __shared__ short Bs[256 * 64];  // Mt d rows
  const int b = blockIdx.x, m0 = blockIdx.y * 32;
  const int tid = threadIdx.x, wave = tid >> 6, lane = tid & 63;
  const int ln = lane & 15, kg = lane >> 4;
  const short* Ab = xb + (size_t)b * ((size_t)NN * DD);
  const short* Bb = Mtb + (size_t)b * ((size_t)DD * DD);
  const size_t base = (size_t)b * ((size_t)NN * DD);

  f32x4 acc[2][4];
#pragma unroll
  for (int i = 0; i < 2; ++i)
#pragma unroll
    for (int j = 0; j < 4; ++j) acc[i][j] = (f32x4){0.f, 0.f, 0.f, 0.f};

  for (int k0 = 0; k0 < DD; k0 += 64) {
    __syncthreads();
    {
      int row = wave * 8 + (lane >> 3);
      int sg = (lane & 7) ^ (row & 7);
      GLDS(Ab + (size_t)(m0 + row) * DD + k0 + sg * 8, &As[(wave * 8) * 64]);
    }
#pragma unroll
    for (int c = 0; c < 8; ++c) {
      int row = wave * 64 + c * 8 + (lane >> 3);
      int sg = (lane & 7) ^ (row & 7);
      GLDS(Bb + (size_t)row * DD + k0 + sg * 8, &Bs[(wave * 64 + c * 8) * 64]);
    }
    __syncthreads();
    bf16x8 af[2][2], bfr[4][2];
#pragma unroll
    for (int i = 0; i < 2; ++i)
#pragma unroll
      for (int kk = 0; kk < 2; ++kk) {
        int rowA = i * 16 + ln;
        af[i][kk] = *(const bf16x8*)&As[rowA * 64 + (((kk * 4 + kg) ^ (rowA & 7)) * 8)];
      }
#pragma unroll
    for (int j = 0; j < 4; ++j)
#pragma unroll
      for (int kk = 0; kk < 2; ++kk) {
        int rowB = wave * 64 + j * 16 + ln;
        bfr[j][kk] = *(const bf16x8*)&Bs[rowB * 64 + (((kk * 4 + kg) ^ (rowB & 7)) * 8)];
      }
#pragma unroll
    for (int kk = 0; kk < 2; ++kk)
#pragma unroll
      for (int i = 0; i < 2; ++i)
#pragma unroll
        for (int j = 0; j < 4; ++j)
          acc[i][j] = __builtin_amdgcn_mfma_f32_16x16x32_bf16(af[i][kk], bfr[j][kk],
                                                              acc[i][j], 0, 0, 0);
  }
  __syncthreads();
  float* red = (float*)As;  // [0..127] partials, [128..159] M, [160..191] lse

  const float a0 = P[kiter], rho = P[8 + kiter], mu = P[12 + kiter];
  const float inv = 1.0f / (rho + a0);
  float y[2][4][4];
#pragma unroll
  for (int i = 0; i < 2; ++i)
#pragma unroll
    for (int j = 0; j < 4; ++j) {
      int d = wave * 64 + j * 16 + ln;
      int n4 = m0 + i * 16 + kg * 4;
      size_t idx = base + (size_t)d * NN + n4;
      u16x4 zv = *(const u16x4*)&zb[idx];
      u16x4 es = *(const u16x4*)&eST[idx];
#pragma unroll
      for (int q = 0; q < 4; ++q)
        y[i][j][q] = (acc[i][j][q] + b2f(zv[q]) + rho * logf(b2f(es[q]))) * inv;
    }
  // softmax over d: in-lane j -> ln shfl -> 4 waves LDS
  float pm[2][4];
#pragma unroll
  for (int i = 0; i < 2; ++i)
#pragma unroll
    for (int q = 0; q < 4; ++q) {
      float m = fmaxf(fmaxf(y[i][0][q], y[i][1][q]), fmaxf(y[i][2][q], y[i][3][q]));
      m = fmaxf(m, __shfl_xor(m, 1));
      m = fmaxf(m, __shfl_xor(m, 2));
      m = fmaxf(m, __shfl_xor(m, 4));
      m = fmaxf(m, __shfl_xor(m, 8));
      pm[i][q] = m;
    }
  if (ln == 0) {
#pragma unroll
    for (int i = 0; i < 2; ++i)
#pragma unroll
      for (int q = 0; q < 4; ++q) red[wave * 32 + i * 16 + kg * 4 + q] = pm[i][q];
  }
  __syncthreads();
  if (tid < 32)
    red[128 + tid] = fmaxf(fmaxf(red[tid], red[32 + tid]),
                           fmaxf(red[64 + tid], red[96 + tid]));
  __syncthreads();
  float sm[2][4], mc[2][4];
#pragma unroll
  for (int i = 0; i < 2; ++i)
#pragma unroll
    for (int q = 0; q < 4; ++q) {
      mc[i][q] = red[128 + i * 16 + kg * 4 + q];
      float s = expf(y[i][0][q] - mc[i][q]) + expf(y[i][1][q] - mc[i][q]) +
                expf(y[i][2][q] - mc[i][q]) + expf(y[i][3][q] - mc[i][q]);
      s += __shfl_xor(s, 1);
      s += __shfl_xor(s, 2);
      s += __shfl_xor(s, 4);
      s += __shfl_xor(s, 8);
      sm[i][q] = s;
    }
  __syncthreads();
  if (ln == 0) {
#pragma unroll
    for (int i = 0; i < 2; ++i)
#pragma unroll
      for (int q = 0; q < 4; ++q) red[wave * 32 + i * 16 + kg * 4 + q] = sm[i][q];
  }
  __syncthreads();
  if (tid < 32)
    red[160 + tid] = red[128 + tid] +
                     logf(red[tid] + red[32 + tid] + red[64 + tid] + red[96 + tid]);
  __syncthreads();
  float lse[2][4];
#pragma unroll
  for (int i = 0; i < 2; ++i)
#pragma unroll
    for (int q = 0; q < 4; ++q) lse[i][q] = red[160 + i * 16 + kg * 4 + q];

  if (LAST == 0) {
#pragma unroll
    for (int i = 0; i < 2; ++i)
#pragma unroll
      for (int j = 0; j < 4; ++j) {
        int d = wave * 64 + j * 16 + ln;
        int n4 = m0 + i * 16 + kg * 4;
        size_t idx = base + (size_t)d * NN + n4;
        u16x4 et;
#pragma unroll
        for (int q = 0; q < 4; ++q) et[q] = f2b(expf(mu + y[i][j][q] - lse[i][q]));
        *(u16x4*)&eTT[idx] = et;
      }
  } else {
    float p[4] = {0.f, 0.f, 0.f, 0.f};
#pragma unroll
    for (int j = 0; j < 4; ++j)
#pragma unroll
      for (int i = 0; i < 2; ++i) {
        int d = wave * 64 + j * 16 + ln;
        int n4 = m0 + i * 16 + kg * 4;
        size_t idx = base + (size_t)d * NN + n4;
        u16x4 xv = *(const u16x4*)&xTb[idx];
#pragma unroll
        for (int q = 0; q < 4; ++q)
          p[j] += b2f(xv[q]) * expf(mu + y[i][j][q] - lse[i][q]);
      }
#pragma unroll
    for (int j = 0; j < 4; ++j) {
      p[j] += __shfl_xor(p[j], 16);
      p[j] += __shfl_xor(p[j], 32);
    }
    if (kg == 0) {
      size_t pb = ((size_t)b * 16 + blockIdx.y) * DD;
#pragma unroll
      for (int j = 0; j < 4; ++j) part[pb + wave * 64 + j * 16 + ln] = p[j];
    }
  }
}

// ---------- fused S-half (k<=2): GEMM(x@Mt_S) + S-softmax(axis=n) + z-update ----------
// grid (BATCH, 8): d-tile 32, all 512 n. 8 waves; wave owns n in [w*64,(w+1)*64).
template <int ZFIRST>
__global__ __launch_bounds__(512) void k_fs(
    const short* __restrict__ xb, const short* __restrict__ Mtb,
    const short* __restrict__ eTT, short* __restrict__ eST,
    short* __restrict__ zb, const float* __restrict__ P, int kiter) {
  __shared__ short As[512 * 32];  // xb all n, BK=32
  __shared__ short Bs[32 * 32];   // Mt d-tile
  const int b = blockIdx.x, m0 = blockIdx.y * 32;
  const int tid = threadIdx.x, wave = tid >> 6, lane = tid & 63;
  const int ln = lane & 15, kg = lane >> 4;
  const short* Ab = xb + (size_t)b * ((size_t)NN * DD);
  const short* Bb = Mtb + (size_t)b * ((size_t)DD * DD);
  const size_t base = (size_t)b * ((size_t)NN * DD);

  f32x4 acc[4][2];
#pragma unroll
  for (int i = 0; i < 4; ++i)
#pragma unroll
    for (int j = 0; j < 2; ++j) acc[i][j] = (f32x4){0.f, 0.f, 0.f, 0.f};

  for (int k0 = 0; k0 < DD; k0 += 32) {
    __syncthreads();
#pragma unroll
    for (int c = 0; c < 4; ++c) {
      int row = wave * 64 + c * 16 + (lane >> 2);
      int sg = (lane & 3) ^ (row & 3);
      GLDS(Ab + (size_t)row * DD + k0 + sg * 8, &As[(wave * 64 + c * 16) * 32]);
    }
    if (wave < 2) {
      int row = wave * 16 + (lane >> 2);
      int sg = (lane & 3) ^ (row & 3);
      GLDS(Bb + (size_t)(m0 + row) * DD + k0 + sg * 8, &Bs[(wave * 16) * 32]);
    }
    __syncthreads();
    bf16x8 af[4], bfr[2];
#pragma unroll
    for (int i = 0; i < 4; ++i) {
      int rowA = wave * 64 + i * 16 + ln;
      af[i] = *(const bf16x8*)&As[rowA * 32 + ((kg ^ (rowA & 3)) * 8)];
    }
#pragma unroll
    for (int j = 0; j < 2; ++j) {
      int rowB = j * 16 + ln;
      bfr[j] = *(const bf16x8*)&Bs[rowB * 32 + ((kg ^ (rowB & 3)) * 8)];
    }
#pragma unroll
    for (int i = 0; i < 4; ++i)
#pragma unroll
      for (int j = 0; j < 2; ++j)
        acc[i][j] = __builtin_amdgcn_mfma_f32_16x16x32_bf16(af[i], bfr[j], acc[i][j], 0, 0, 0);
  }
  __syncthreads();
  float* red = (float*)Bs;  // [0..255] partials, [256..287] M, [288..319] lse

  const float rho = P[8 + kiter], eta = P[16 + kiter];
  const float invr = 1.0f / rho;
  float y[4][2][4];
  u16x4 etr[4][2], zr[4][2];
#pragma unroll
  for (int i = 0; i < 4; ++i)
#pragma unroll
    for (int j = 0; j < 2; ++j) {
      int d = m0 + j * 16 + ln;
      int n4 = wave * 64 + i * 16 + kg * 4;
      size_t idx = base + (size_t)d * NN + n4;
      etr[i][j] = *(const u16x4*)&eTT[idx];
      if (!ZFIRST) zr[i][j] = *(const u16x4*)&zb[idx];
#pragma unroll
      for (int q = 0; q < 4; ++q) {
        float zf = ZFIRST ? 0.0f : b2f(zr[i][j][q]);
        y[i][j][q] = (acc[i][j][q] - zf + rho * logf(b2f(etr[i][j][q]))) * invr;
      }
    }
  // softmax over n: in-lane (i,q) -> kg shfl -> 8 waves LDS
  float pm[2];
#pragma unroll
  for (int j = 0; j < 2; ++j) {
    float m = -1e30f;
#pragma unroll
    for (int i = 0; i < 4; ++i)
#pragma unroll
      for (int q = 0; q < 4; ++q) m = fmaxf(m, y[i][j][q]);
    m = fmaxf(m, __shfl_xor(m, 16));
    m = fmaxf(m, __shfl_xor(m, 32));
    pm[j] = m;
  }
  if (kg == 0) {
#pragma unroll
    for (int j = 0; j < 2; ++j) red[wave * 32 + j * 16 + ln] = pm[j];
  }
  __syncthreads();
  if (tid < 32) {
    float M = red[tid];
#pragma unroll
    for (int w = 1; w < 8; ++w) M = fmaxf(M, red[w * 32 + tid]);
    red[256 + tid] = M;
  }
  __syncthreads();
  float mc[2], ps[2];
#pragma unroll
  for (int j = 0; j < 2; ++j) {
    mc[j] = red[256 + j * 16 + ln];
    float s = 0.f;
#pragma unroll
    for (int i = 0; i < 4; ++i)
#pragma unroll
      for (int q = 0; q < 4; ++q) s += expf(y[i][j][q] - mc[j]);
    s += __shfl_xor(s, 16);
    s += __shfl_xor(s, 32);
    ps[j] = s;
  }
  __syncthreads();
  if (kg == 0) {
#pragma unroll
    for (int j = 0; j < 2; ++j) red[wave * 32 + j * 16 + ln] = ps[j];
  }
  __syncthreads();
  if (tid < 32) {
    float S = 0.f;
#pragma unroll
    for (int w = 0; w < 8; ++w) S += red[w * 32 + tid];
    red[288 + tid] = red[256 + tid] + logf(S);
  }
  __syncthreads();
  float lse[2];
#pragma unroll
  for (int j = 0; j < 2; ++j) lse[j] = red[288 + j * 16 + ln];

#pragma unroll
  for (int i = 0; i < 4; ++i)
#pragma unroll
    for (int j = 0; j < 2; ++j) {
      int d = m0 + j * 16 + ln;
      int n4 = wave * 64 + i * 16 + kg * 4;
      size_t idx = base + (size_t)d * NN + n4;
      u16x4 ev, zo;
#pragma unroll
      for (int q = 0; q < 4; ++q) {
        float es = expf(eta + y[i][j][q] - lse[j]);
        ev[q] = f2b(es);
        float zf = ZFIRST ? 0.0f : b2f(zr[i][j][q]);
        zo[q] = f2b(zf + rho * (b2f(etr[i][j][q]) - es));
      }
      *(u16x4*)&eST[idx] = ev;
      *(u16x4*)&zb[idx] = zo;
    }
}

// ---------- final reduce: out[b][d] = D * sum over 16 partial chunks ----------
__global__ __launch_bounds__(256) void k_out2(const float* __restrict__ part,
                                              float* __restrict__ out) {
  int b = blockIdx.x, d = threadIdx.x;
  float acc = 0.0f;
#pragma unroll
  for (int c = 0; c < 16; ++c) acc += part[((size_t)b * 16 + c) * DD + d];
  out[(size_t)b * DD + d] = (float)DD * acc;
}

// ---------- launch ----------
extern "C" void kernel_launch(void* const* d_in, const int* in_sizes, int n_in,
                              void* d_out, int out_size, void* d_ws, size_t ws_size,
                              hipStream_t stream) {
  const float* x = (const float*)d_in[0];
  const float* a0p = (const float*)d_in[1];
  const float* a1p = (const float*)d_in[2];
  const float* a2p = (const float*)d_in[3];
  const float* a3p = (const float*)d_in[4];
  const float* rhop = (const float*)d_in[5];
  float* out = (float*)d_out;

  const size_t NE = (size_t)BATCH * NN * DD;
  const size_t NE_b = (size_t)NN * DD;
  const size_t C1_b = (size_t)DD * DD;

  float* fws = (float*)d_ws;
  float* S = fws;                   // B*D colsum(x)
  float* s1 = S + BATCH * DD;       // B*D rowsum(c1)
  float* part = s1 + BATCH * DD;    // B*16*DD
  float* P = part + BATCH * 16 * DD;  // 24
  unsigned* keys = (unsigned*)(P + 24);
  short* sws = (short*)(keys + 8);
  short* xb = sws;                  // NE (n-major bf16)
  short* xTb = sws + NE;            // NE (d-major bf16)
  short* eTT = sws + 2 * NE;        // NE (d-major)
  short* eST = sws + 3 * NE;        // NE (d-major)
  short* zb = sws + 4 * NE;         // NE (d-major bf16 dual)
  short* Fb = sws + 5 * NE;         // B*D*D
  short* Mtb = Fb + (size_t)BATCH * C1_b;   // B*D*D
  short* c1b = Mtb + (size_t)BATCH * C1_b;  // B*D*D

  k_prep<<<dim3(4, 8, BATCH), 256, 0, stream>>>(x, xb, xTb, keys);
  k_gemm<512, 0><<<dim3(BATCH, 4, 4), 256, 0, stream>>>(
      xTb, NE_b, NN, xTb, NE_b, NN, (void*)c1b, C1_b, DD, 1.0f / NN, keys + 0,
      nullptr, 0);
  k_c2max<<<dim3(BATCH, 8, 8), 256, 0, stream>>>(xb, keys + 1);
  k_misc<<<2081, 256, 0, stream>>>(c1b, xb, s1, S, a0p, a1p, a2p, a3p, rhop, P, keys);

  // k = 0 T-half: rank-1 shortcut -> eTT
  k_tsm0<<<dim3(BATCH, 8), 512, 0, stream>>>(xTb, S, s1, eTT, P);
  // k = 0 S-half
  k_gemm<512, 1><<<dim3(BATCH, 4, 4), 256, 0, stream>>>(
      xTb, NE_b, NN, eTT, NE_b, NN, (void*)Fb, C1_b, DD, 1.0f, nullptr, nullptr, 0);
  k_gemm<256, 2><<<dim3(BATCH, 4, 4), 256, 0, stream>>>(
      Fb, C1_b, DD, c1b, C1_b, DD, (void*)Mtb, C1_b, DD, 0.f, nullptr, P, 0);
  k_fs<1><<<dim3(BATCH, 8), 512, 0, stream>>>(xb, Mtb, eTT, eST, zb, P, 0);

  for (int k = 1; k <= 2; ++k) {
    // T-half: Mt_T = (a1e/D)(F(eS)@c1)^T + I; fused GEMM+softmax -> eTT
    k_gemm<512, 1><<<dim3(BATCH, 4, 4), 256, 0, stream>>>(
        xTb, NE_b, NN, eST, NE_b, NN, (void*)Fb, C1_b, DD, 1.0f, nullptr, nullptr, 0);
    k_gemm<256, 3><<<dim3(BATCH, 4, 4), 256, 0, stream>>>(
        Fb, C1_b, DD, c1b, C1_b, DD, (void*)Mtb, C1_b, DD, 0.f, nullptr, P, k);
    k_ft<0><<<dim3(BATCH, 16), 256, 0, stream>>>(xb, Mtb, eST, zb, eTT, xTb,
                                                 part, P, k);
    // S-half
    k_gemm<512, 1><<<dim3(BATCH, 4, 4), 256, 0, stream>>>(
        xTb, NE_b, NN, eTT, NE_b, NN, (void*)Fb, C1_b, DD, 1.0f, nullptr, nullptr, 0);
    k_gemm<256, 2><<<dim3(BATCH, 4, 4), 256, 0, stream>>>(
        Fb, C1_b, DD, c1b, C1_b, DD, (void*)Mtb, C1_b, DD, 0.f, nullptr, P, k);
    k_fs<0><<<dim3(BATCH, 8), 512, 0, stream>>>(xb, Mtb, eTT, eST, zb, P, k);
  }

  // k = 3: final T-half -> output partials (tail-trim: S-half dead)
  k_gemm<512, 1><<<dim3(BATCH, 4, 4), 256, 0, stream>>>(
      xTb, NE_b, NN, eST, NE_b, NN, (void*)Fb, C1_b, DD, 1.0f, nullptr, nullptr, 0);
  k_gemm<256, 3><<<dim3(BATCH, 4, 4), 256, 0, stream>>>(
      Fb, C1_b, DD, c1b, C1_b, DD, (void*)Mtb, C1_b, DD, 0.f, nullptr, P, 3);
  k_ft<1><<<dim3(BATCH, 16), 256, 0, stream>>>(xb, Mtb, eST, zb, eTT, xTb,
                                               part, P, 3);
  k_out2<<<BATCH, 256, 0, stream>>>(part, out);
}